// Round 3
// baseline (124.894 us; speedup 1.0000x reference)
//
#include <hip/hip_runtime.h>
#include <hip/hip_bf16.h>

// Problem dims (fixed by the reference setup_inputs)
#define BB 8
#define TT 4096
#define SS 256
#define DD 512
#define XROWS (BB * TT)  // 32768
#define YROWS (BB * SS)  // 2048

typedef __attribute__((ext_vector_type(8))) short short8;
typedef __attribute__((ext_vector_type(4))) float floatx4;

__device__ inline short f2bf(float f) {
  // round-to-nearest-even f32 -> bf16 (inputs are finite normals)
  unsigned u = __builtin_bit_cast(unsigned, f);
  u += 0x7fffu + ((u >> 16) & 1u);
  return (short)(u >> 16);
}

// Pack 8 consecutive-k f32 values into a bf16 MFMA fragment.
__device__ inline short8 cvt8(float4 f0, float4 f1) {
  short8 o;
  o[0] = f2bf(f0.x);
  o[1] = f2bf(f0.y);
  o[2] = f2bf(f0.z);
  o[3] = f2bf(f0.w);
  o[4] = f2bf(f1.x);
  o[5] = f2bf(f1.y);
  o[6] = f2bf(f1.z);
  o[7] = f2bf(f1.w);
  return o;
}

// K1: one wave per row; writes ONLY the inverse norms (1/max(||r||, eps)).
// Rows [0, XROWS) are xs_pad, [XROWS, XROWS+YROWS) are spk_emb.
// ws footprint: (32768 + 2048) * 4 B = 140 KB.
__global__ __launch_bounds__(256) void cos_scale_kernel(
    const float* __restrict__ xs, const float* __restrict__ spk,
    float* __restrict__ xscale, float* __restrict__ yscale) {
  const int wave = threadIdx.x >> 6;
  const int lane = threadIdx.x & 63;
  int row = blockIdx.x * 4 + wave;
  const float* src;
  float* dst;
  if (row < XROWS) {
    src = xs + (size_t)row * DD;
    dst = xscale + row;
  } else {
    int r = row - XROWS;
    src = spk + (size_t)r * DD;
    dst = yscale + r;
  }
  const float4* s4 = (const float4*)src + lane * 2;
  float4 a = s4[0];
  float4 b = s4[1];
  float ss = a.x * a.x + a.y * a.y + a.z * a.z + a.w * a.w +
             b.x * b.x + b.y * b.y + b.z * b.z + b.w * b.w;
#pragma unroll
  for (int off = 32; off; off >>= 1) ss += __shfl_xor(ss, off, 64);
  if (lane == 0) *dst = 1.0f / fmaxf(sqrtf(ss), 1e-8f);
}

// K2: C[b] = (bf16(X[b]) * bf16(Y[b])^T) scaled by xscale*yscale in epilogue.
// 128x128 tile, BK=64 f32. A/B staged RAW f32 via global_load_lds width=16
// (32 KB each). XOR-16 swizzle: LDS 16B-slot s of a row holds logical 16B
// block (s ^ (row&15)) -> ds_read_b128 frag reads are bank-uniform.
// Frags converted f32->bf16 in-register.
__global__ __launch_bounds__(256) void cos_gemm_kernel(
    const float* __restrict__ xs, const float* __restrict__ spk,
    const float* __restrict__ xscale, const float* __restrict__ yscale,
    float* __restrict__ out) {
  __shared__ float sA[128 * 64];
  __shared__ float sB[128 * 64];

  const int tid = threadIdx.x;
  const int wave = tid >> 6;
  const int lane = tid & 63;
  const int tn = blockIdx.x;  // 0..1
  const int tm = blockIdx.y;  // 0..31
  const int b = blockIdx.z;   // 0..7

  const float* Abase = xs + ((size_t)b * TT + tm * 128) * DD;
  const float* Bbase = spk + ((size_t)b * SS + tn * 128) * DD;

  floatx4 acc[4][4];
#pragma unroll
  for (int i = 0; i < 4; i++)
#pragma unroll
    for (int j = 0; j < 4; j++) acc[i][j] = (floatx4){0.f, 0.f, 0.f, 0.f};

  const int wm = wave >> 1;
  const int wn = wave & 1;
  const int quad = lane >> 4;
  const int l15 = lane & 15;

  // Staging map: 16B unit s = j*256 + tid; row = s>>4 (16 units/row);
  // slot = s&15 holds logical block (slot ^ (row&15)).
  // Precompute per-j source f32 offsets (row*DD + logical_block*4).
  int aoff[8];
#pragma unroll
  for (int j = 0; j < 8; j++) {
    int s = j * 256 + tid;
    int row = s >> 4;
    int blk = (s & 15) ^ (row & 15);
    aoff[j] = row * DD + blk * 4;
  }

  for (int kt = 0; kt < DD / 64; ++kt) {
#pragma unroll
    for (int j = 0; j < 8; j++) {
      const float* ga = Abase + aoff[j] + kt * 64;
      const float* gb = Bbase + aoff[j] + kt * 64;
      // wave-uniform LDS base; HW scatters lane i at base + i*16
      __builtin_amdgcn_global_load_lds(
          (const __attribute__((address_space(1))) unsigned int*)ga,
          (__attribute__((address_space(3))) unsigned int*)(sA +
              (j * 256 + wave * 64) * 4),
          16, 0, 0);
      __builtin_amdgcn_global_load_lds(
          (const __attribute__((address_space(1))) unsigned int*)gb,
          (__attribute__((address_space(3))) unsigned int*)(sB +
              (j * 256 + wave * 64) * 4),
          16, 0, 0);
    }
    __syncthreads();

#pragma unroll
    for (int ks = 0; ks < 2; ks++) {
      short8 af[4], bf[4];
      const int b0 = ks * 8 + quad * 2;  // first 16B block of the frag's 8 f32
#pragma unroll
      for (int im = 0; im < 4; im++) {
        int row = wm * 64 + im * 16 + l15;
        int s0 = b0 ^ (row & 15);
        int s1 = (b0 + 1) ^ (row & 15);
        float4 f0 = *(const float4*)(sA + row * 64 + s0 * 4);
        float4 f1 = *(const float4*)(sA + row * 64 + s1 * 4);
        af[im] = cvt8(f0, f1);
      }
#pragma unroll
      for (int in = 0; in < 4; in++) {
        int row = wn * 64 + in * 16 + l15;
        int s0 = b0 ^ (row & 15);
        int s1 = (b0 + 1) ^ (row & 15);
        float4 f0 = *(const float4*)(sB + row * 64 + s0 * 4);
        float4 f1 = *(const float4*)(sB + row * 64 + s1 * 4);
        bf[in] = cvt8(f0, f1);
      }
#pragma unroll
      for (int im = 0; im < 4; im++)
#pragma unroll
        for (int in = 0; in < 4; in++)
          acc[im][in] = __builtin_amdgcn_mfma_f32_16x16x32_bf16(
              af[im], bf[in], acc[im][in], 0, 0, 0);
    }
    __syncthreads();
  }

  // Epilogue: C/D layout col = lane&15, row = quad*4 + reg; apply cosine
  // scales here (dot(x,y) * (1/||x||) * (1/||y||)).
  float* Obase = out + ((size_t)b * TT + tm * 128) * SS + tn * 128;
  const float* xsc = xscale + b * TT + tm * 128;
  const float* ysc = yscale + b * SS + tn * 128;
#pragma unroll
  for (int im = 0; im < 4; im++) {
#pragma unroll
    for (int in = 0; in < 4; in++) {
      int col = wn * 64 + in * 16 + l15;
      float yv = ysc[col];
#pragma unroll
      for (int r = 0; r < 4; r++) {
        int row = wm * 64 + im * 16 + quad * 4 + r;
        Obase[row * SS + col] = acc[im][in][r] * xsc[row] * yv;
      }
    }
  }
}

extern "C" void kernel_launch(void* const* d_in, const int* in_sizes, int n_in,
                              void* d_out, int out_size, void* d_ws,
                              size_t ws_size, hipStream_t stream) {
  const float* xs = (const float*)d_in[0];   // (8,4096,512) f32
  const float* spk = (const float*)d_in[1];  // (8,256,512) f32
  float* out = (float*)d_out;                // (8,4096,256) f32

  float* xscale = (float*)d_ws;              // 32768 f32
  float* yscale = xscale + XROWS;            // 2048 f32  (total 140 KB ws)

  hipLaunchKernelGGL(cos_scale_kernel, dim3((XROWS + YROWS) / 4), dim3(256), 0,
                     stream, xs, spk, xscale, yscale);
  hipLaunchKernelGGL(cos_gemm_kernel, dim3(SS / 128, TT / 128, BB), dim3(256),
                     0, stream, xs, spk, xscale, yscale, out);
}

// Round 4
// 123.760 us; speedup vs baseline: 1.0092x; 1.0092x over previous
//
#include <hip/hip_runtime.h>
#include <hip/hip_bf16.h>

// Problem dims (fixed by the reference setup_inputs)
#define BB 8
#define TT 4096
#define SS 256
#define DD 512

typedef __attribute__((ext_vector_type(8))) short short8;
typedef __attribute__((ext_vector_type(4))) float floatx4;

__device__ inline short f2bf(float f) {
  // round-to-nearest-even f32 -> bf16 (inputs are finite normals)
  unsigned u = __builtin_bit_cast(unsigned, f);
  u += 0x7fffu + ((u >> 16) & 1u);
  return (short)(u >> 16);
}

// Pack 8 consecutive-k f32 values into a bf16 MFMA fragment.
__device__ inline short8 cvt8(float4 f0, float4 f1) {
  short8 o;
  o[0] = f2bf(f0.x);
  o[1] = f2bf(f0.y);
  o[2] = f2bf(f0.z);
  o[3] = f2bf(f0.w);
  o[4] = f2bf(f1.x);
  o[5] = f2bf(f1.y);
  o[6] = f2bf(f1.z);
  o[7] = f2bf(f1.w);
  return o;
}

__device__ inline float sq8(float4 f0, float4 f1) {
  return f0.x * f0.x + f0.y * f0.y + f0.z * f0.z + f0.w * f0.w +
         f1.x * f1.x + f1.y * f1.y + f1.z * f1.z + f1.w * f1.w;
}

// Fully fused cosine scorer:
//   C[b] = diag(1/||x||) * (bf16(X[b]) * bf16(Y[b])^T) * diag(1/||y||)
// 128x128 tile, BK=64 f32. A/B staged RAW f32 via global_load_lds width=16
// (32 KB each, 64 KB LDS -> 2 blocks/CU). XOR-16 swizzle: LDS 16B-slot s of a
// row holds logical block (s ^ (row&15)) -> ds_read_b128 frags bank-uniform.
// Row/col inverse norms are accumulated IN-TILE during the frag-read phase
// (the (ks,quad) enumeration covers each row's K-tile exactly once per wave),
// reduced across quads via shfl_xor, applied in the epilogue. No workspace.
__global__ __launch_bounds__(256) void cos_fused_kernel(
    const float* __restrict__ xs, const float* __restrict__ spk,
    float* __restrict__ out) {
  __shared__ float sA[128 * 64];
  __shared__ float sB[128 * 64];
  __shared__ float scX[128];
  __shared__ float scY[128];

  const int tid = threadIdx.x;
  const int wave = tid >> 6;
  const int lane = tid & 63;
  const int tn = blockIdx.x;  // 0..1
  const int tm = blockIdx.y;  // 0..31
  const int b = blockIdx.z;   // 0..7

  const float* Abase = xs + ((size_t)b * TT + tm * 128) * DD;
  const float* Bbase = spk + ((size_t)b * SS + tn * 128) * DD;

  floatx4 acc[4][4];
#pragma unroll
  for (int i = 0; i < 4; i++)
#pragma unroll
    for (int j = 0; j < 4; j++) acc[i][j] = (floatx4){0.f, 0.f, 0.f, 0.f};

  float sx[4] = {0.f, 0.f, 0.f, 0.f};
  float sy[4] = {0.f, 0.f, 0.f, 0.f};

  const int wm = wave >> 1;
  const int wn = wave & 1;
  const int quad = lane >> 4;
  const int l15 = lane & 15;

  // Staging map: 16B unit s = j*256 + tid; row = s>>4 (16 units/row);
  // slot = s&15 holds logical block (slot ^ (row&15)).
  int aoff[8];
#pragma unroll
  for (int j = 0; j < 8; j++) {
    int s = j * 256 + tid;
    int row = s >> 4;
    int blk = (s & 15) ^ (row & 15);
    aoff[j] = row * DD + blk * 4;
  }

  for (int kt = 0; kt < DD / 64; ++kt) {
#pragma unroll
    for (int j = 0; j < 8; j++) {
      const float* ga = Abase + aoff[j] + kt * 64;
      const float* gb = Bbase + aoff[j] + kt * 64;
      // wave-uniform LDS base; HW scatters lane i at base + i*16
      __builtin_amdgcn_global_load_lds(
          (const __attribute__((address_space(1))) unsigned int*)ga,
          (__attribute__((address_space(3))) unsigned int*)(sA +
              (j * 256 + wave * 64) * 4),
          16, 0, 0);
      __builtin_amdgcn_global_load_lds(
          (const __attribute__((address_space(1))) unsigned int*)gb,
          (__attribute__((address_space(3))) unsigned int*)(sB +
              (j * 256 + wave * 64) * 4),
          16, 0, 0);
    }
    __syncthreads();

#pragma unroll
    for (int ks = 0; ks < 2; ks++) {
      short8 af[4], bf[4];
      const int b0 = ks * 8 + quad * 2;  // first 16B block of the frag's 8 f32
#pragma unroll
      for (int im = 0; im < 4; im++) {
        int row = wm * 64 + im * 16 + l15;
        int s0 = b0 ^ (row & 15);
        int s1 = (b0 + 1) ^ (row & 15);
        float4 f0 = *(const float4*)(sA + row * 64 + s0 * 4);
        float4 f1 = *(const float4*)(sA + row * 64 + s1 * 4);
        sx[im] += sq8(f0, f1);
        af[im] = cvt8(f0, f1);
      }
#pragma unroll
      for (int in = 0; in < 4; in++) {
        int row = wn * 64 + in * 16 + l15;
        int s0 = b0 ^ (row & 15);
        int s1 = (b0 + 1) ^ (row & 15);
        float4 f0 = *(const float4*)(sB + row * 64 + s0 * 4);
        float4 f1 = *(const float4*)(sB + row * 64 + s1 * 4);
        sy[in] += sq8(f0, f1);
        bf[in] = cvt8(f0, f1);
      }
#pragma unroll
      for (int im = 0; im < 4; im++)
#pragma unroll
        for (int in = 0; in < 4; in++)
          acc[im][in] = __builtin_amdgcn_mfma_f32_16x16x32_bf16(
              af[im], bf[in], acc[im][in], 0, 0, 0);
    }
    __syncthreads();
  }

  // Per-row sumsq: each wave's lanes {l15, l15+16, l15+32, l15+48} hold the
  // 4 quad-partials of row (w*64 + i*16 + l15) — butterfly over xor 16, 32.
#pragma unroll
  for (int i = 0; i < 4; i++) {
    sx[i] += __shfl_xor(sx[i], 16, 64);
    sx[i] += __shfl_xor(sx[i], 32, 64);
    sy[i] += __shfl_xor(sy[i], 16, 64);
    sy[i] += __shfl_xor(sy[i], 32, 64);
  }
  if (quad == 0) {
#pragma unroll
    for (int i = 0; i < 4; i++) {
      scX[wm * 64 + i * 16 + l15] = 1.0f / fmaxf(sqrtf(sx[i]), 1e-8f);
      scY[wn * 64 + i * 16 + l15] = 1.0f / fmaxf(sqrtf(sy[i]), 1e-8f);
    }
  }
  __syncthreads();

  // Epilogue: C/D layout col = lane&15, row = quad*4 + reg; apply cosine
  // scales (dot * (1/||x||) * (1/||y||)).
  float* Obase = out + ((size_t)b * TT + tm * 128) * SS + tn * 128;
#pragma unroll
  for (int im = 0; im < 4; im++) {
#pragma unroll
    for (int in = 0; in < 4; in++) {
      int col = wn * 64 + in * 16 + l15;
      float yv = scY[col];
#pragma unroll
      for (int r = 0; r < 4; r++) {
        int row = wm * 64 + im * 16 + quad * 4 + r;
        Obase[row * SS + col] = acc[im][in][r] * scX[row] * yv;
      }
    }
  }
}

extern "C" void kernel_launch(void* const* d_in, const int* in_sizes, int n_in,
                              void* d_out, int out_size, void* d_ws,
                              size_t ws_size, hipStream_t stream) {
  const float* xs = (const float*)d_in[0];   // (8,4096,512) f32
  const float* spk = (const float*)d_in[1];  // (8,256,512) f32
  float* out = (float*)d_out;                // (8,4096,256) f32

  hipLaunchKernelGGL(cos_fused_kernel, dim3(SS / 128, TT / 128, BB), dim3(256),
                     0, stream, xs, spk, out);
}